// Round 2
// baseline (22924.870 us; speedup 1.0000x reference)
//
#include <hip/hip_runtime.h>

#define B     16
#define TENC  128
#define TDEC  100
#define IND   256
#define HID   256
#define OD    400
#define MD    80
#define LBUF  17
#define BD    336      // IN_DIM + MEM_DIM
#define BS    5712     // LBUF * BD
#define BH    571      // BUF_SIZE // 10
#define MH    40       // OUT_DIM // 10
#define NSLOT 117      // TDEC + 17 u-history slots

// workspace layout (float offsets)
#define OFF_U    0
#define SZ_U     (NSLOT*B*BD)          // 628992  u history: slot s holds u_{s-17}
#define OFF_PA   (OFF_U + SZ_U)
#define SZ_PA    (B*TENC*HID)          // 524288  processed annotations
#define OFF_MEM  (OFF_PA + SZ_PA)
#define SZ_MEM   (TDEC*B*MD)           // 128000  mem projections, all steps
#define OFF_M    (OFF_MEM + SZ_MEM)
#define SZ_M     (LBUF*BD*OD)          // 2284800 fused scale_w x out_w
#define OFF_CO   (OFF_M + SZ_M)
#define SZ_CO    (OD)                  // fused constant output bias
#define OFF_P    (OFF_CO + SZ_CO)
#define SZ_P     (8*B*832)             // 106496  K-split partials for pq|S

__global__ __launch_bounds__(256) void k_init(float* __restrict__ ws) {
    int i = blockIdx.x*256 + threadIdx.x;
    if (i < 17*B*BD) ws[OFF_U + i] = 0.f;                 // u_{-17..-1} = 0
    else if (i < 17*B*BD + OD) ws[OFF_CO + (i - 17*B*BD)] = 0.f;
}

// pa[b,j,h] = inputs[b,j,:] @ att_wa[:,h] + att_ba[h]
__global__ __launch_bounds__(256) void k_pa(const float* __restrict__ inputs,
        const float* __restrict__ wa, const float* __restrict__ ba,
        float* __restrict__ ws) {
    int bj = blockIdx.x;
    int tid = threadIdx.x;
    __shared__ float xin[IND];
    xin[tid] = inputs[bj*IND + tid];
    __syncthreads();
    float acc = ba[tid];
    #pragma unroll 4
    for (int i = 0; i < IND; i++) acc += xin[i]*wa[i*HID + tid];
    ws[OFF_PA + bj*HID + tid] = acc;
}

// mem_p for every step: relu(mem @ mp_w1 + b1) @ mp_w2 + b2, mem = targets[:,t-1] (0 at t=0)
__global__ __launch_bounds__(128) void k_mem(const float* __restrict__ targets,
        const float* __restrict__ w1, const float* __restrict__ b1,
        const float* __restrict__ w2, const float* __restrict__ b2,
        float* __restrict__ ws) {
    int tb = blockIdx.x; int t = tb / B; int b = tb % B;
    int tid = threadIdx.x;
    __shared__ float xin[OD];
    __shared__ float hid[MH];
    for (int k = tid; k < OD; k += 128)
        xin[k] = (t == 0) ? 0.f : targets[(b*TDEC + (t-1))*OD + k];
    __syncthreads();
    if (tid < MH) {
        float a = b1[tid];
        for (int k = 0; k < OD; k++) a += xin[k]*w1[k*MH + tid];
        hid[tid] = fmaxf(a, 0.f);
    }
    __syncthreads();
    if (tid < MD) {
        float a = b2[tid];
        #pragma unroll
        for (int k = 0; k < MH; k++) a += hid[k]*w2[k*MD + tid];
        ws[OFF_MEM + (t*B + b)*MD + tid] = a;
    }
}

// M[l][d][o] = sum_h scale_w[h][d] * out_w[l*256+h][o]
__global__ __launch_bounds__(256) void k_M(const float* __restrict__ scale_w,
        const float* __restrict__ out_w, float* __restrict__ ws) {
    int l  = blockIdx.x / 14;
    int d0 = (blockIdx.x % 14) * 24;
    int tid = threadIdx.x;
    __shared__ float sw[HID*24];
    for (int idx = tid; idx < HID*24; idx += 256) {
        int h = idx / 24, dl = idx % 24;
        sw[idx] = scale_w[h*BD + d0 + dl];
    }
    __syncthreads();
    int o0 = tid, o1 = tid + 256;
    bool v1 = o1 < OD;
    float a0[24], a1[24];
    #pragma unroll
    for (int i = 0; i < 24; i++) { a0[i] = 0.f; a1[i] = 0.f; }
    const float* owl = out_w + l*HID*OD;
    for (int h = 0; h < HID; h++) {
        float w0 = owl[h*OD + o0];
        float w1v = v1 ? owl[h*OD + o1] : 0.f;
        #pragma unroll
        for (int dl = 0; dl < 24; dl++) {
            float s = sw[h*24 + dl];
            a0[dl] += s*w0; a1[dl] += s*w1v;
        }
    }
    float* Mp = ws + OFF_M + l*BD*OD;
    for (int dl = 0; dl < 24; dl++) {
        Mp[(d0+dl)*OD + o0] = a0[dl];
        if (v1) Mp[(d0+dl)*OD + o1] = a1[dl];
    }
}

// c_out[o] = out_b[o] + sum_{l,h} scale_b[h]*out_w[l*256+h][o]   (atomic over l)
__global__ __launch_bounds__(256) void k_cout(const float* __restrict__ scale_b,
        const float* __restrict__ out_w, const float* __restrict__ out_b,
        float* __restrict__ ws) {
    int l = blockIdx.x; int tid = threadIdx.x;
    for (int p = 0; p < 2; p++) {
        int o = tid + p*256;
        if (o < OD) {
            float acc = (l == 0) ? out_b[o] : 0.f;
            for (int h = 0; h < HID; h++) acc += scale_b[h]*out_w[(l*HID + h)*OD + o];
            atomicAdd(&ws[OFF_CO + o], acc);
        }
    }
}

// Per step t: K-split partials of
//   pq[b,h] = sum_{w=0..16,d} U[t+w][b][d] * att_wq[((16-w)*336+d)*256 + h]
//   S[b,c]  = sum_{w=1..16,d} U[t+w][b][d] * bp_w1 [((17-w)*336+d)*571 + c]
// grid 104 = 8 K-chunks x 13 column tiles of 64; each thread does 4 batch rows.
__global__ __launch_bounds__(256) void k_step1(const float* __restrict__ wq,
        const float* __restrict__ w1, float* __restrict__ ws, int t) {
    int ct = blockIdx.x % 13;
    int kc = blockIdx.x / 13;
    int tid = threadIdx.x;
    const int k0 = kc * 714;
    __shared__ float U[16*714];
    const float* uh = ws + OFF_U;
    for (int idx = tid; idx < 16*714; idx += 256) {
        int b = idx / 714, kk = idx % 714;
        int k = k0 + kk, w = k / 336, d = k - 336*w;
        U[b*714 + kk] = uh[((t + w)*B + b)*BD + d];
    }
    __syncthreads();
    int col = tid & 63, bg = tid >> 6;
    int gcol = ct*64 + col;          // 0..831 (valid < 827)
    int b0 = bg*4;
    const float* U0 = &U[(b0+0)*714];
    const float* U1 = &U[(b0+1)*714];
    const float* U2 = &U[(b0+2)*714];
    const float* U3 = &U[(b0+3)*714];
    float a0=0.f, a1=0.f, a2=0.f, a3=0.f;
    int w = k0 / 336, d = k0 - 336*w;
    if (gcol < 256) {
        const float* wp = wq + ((16-w)*336 + d)*HID + gcol;
        for (int kk = 0; kk < 714; kk++) {
            float wv = *wp;
            a0 += wv*U0[kk]; a1 += wv*U1[kk]; a2 += wv*U2[kk]; a3 += wv*U3[kk];
            if (++d == 336) { d = 0; wp -= 671*HID; } else wp += HID;
        }
    } else {
        int cS = gcol - 256;
        bool valid = gcol < 827;
        const float* wp = w1 + ((17-w)*336 + d)*BH + cS;
        for (int kk = 0; kk < 714; kk++) {
            float wv = 0.f;
            // z row 0 (k < 336) is `top`, handled in step2; w>=1 <=> global k >= 336.
            // NOTE: w itself is NOT updated in the wrap below (pointer jump encodes it),
            // so the predicate must use k0+kk, not w.
            if (valid && (k0 + kk) >= 336) wv = *wp;
            a0 += wv*U0[kk]; a1 += wv*U1[kk]; a2 += wv*U2[kk]; a3 += wv*U3[kk];
            if (++d == 336) { d = 0; wp -= 671*BH; } else wp += BH;
        }
    }
    float* P = ws + OFF_P;
    P[(kc*B + b0+0)*832 + gcol] = a0;
    P[(kc*B + b0+1)*832 + gcol] = a1;
    P[(kc*B + b0+2)*832 + gcol] = a2;
    P[(kc*B + b0+3)*832 + gcol] = a3;
}

// Per step t, one block per batch: reduce partials, attention, softmax, ctx,
// MLP (h1 -> u), write u into history and attn into d_out.
__global__ __launch_bounds__(512) void k_step2(const float* __restrict__ inputs,
        const float* __restrict__ att_bq, const float* __restrict__ bp_b1,
        const float* __restrict__ bp_w1, const float* __restrict__ bp_b2,
        const float* __restrict__ bp_w2, const float* __restrict__ att_v,
        float* __restrict__ ws, float* __restrict__ attns, int t) {
    int b = blockIdx.x, tid = threadIdx.x;
    __shared__ float pqs[HID];
    __shared__ float Ss[BH];
    __shared__ float sc[TENC];
    __shared__ float attn_s[TENC];
    __shared__ float red[2];
    __shared__ float top[BD];
    __shared__ float h1[BH];
    const float* P = ws + OFF_P;
    for (int col = tid; col < 827; col += 512) {
        float s = 0.f;
        #pragma unroll
        for (int kc = 0; kc < 8; kc++) s += P[(kc*B + b)*832 + col];
        if (col < HID) pqs[col] = s + att_bq[col];
        else           Ss[col - HID] = s + bp_b1[col - HID];
    }
    __syncthreads();
    if (tid < TENC) {
        const float* par = ws + OFF_PA + (b*TENC + tid)*HID;
        float a = 0.f;
        for (int h = 0; h < HID; h++) {
            float x = pqs[h] + par[h];
            a += att_v[h] * tanhf(x);
        }
        sc[tid] = a;
    }
    __syncthreads();
    if (tid == 0) {
        float m = sc[0];
        for (int j = 1; j < TENC; j++) m = fmaxf(m, sc[j]);
        red[0] = m;
    }
    __syncthreads();
    if (tid < TENC) attn_s[tid] = expf(sc[tid] - red[0]);
    __syncthreads();
    if (tid == 0) {
        float s = 0.f;
        for (int j = 0; j < TENC; j++) s += attn_s[j];
        red[1] = 1.f/s;
    }
    __syncthreads();
    if (tid < TENC) {
        float a = attn_s[tid]*red[1];
        attn_s[tid] = a;
        attns[(b*TDEC + t)*TENC + tid] = a;
    }
    __syncthreads();
    if (tid < IND) {
        float c = 0.f;
        for (int j = 0; j < TENC; j++) c += attn_s[j]*inputs[(b*TENC + j)*IND + tid];
        top[tid] = c;
    } else if (tid < BD) {
        top[tid] = ws[OFF_MEM + (t*B + b)*MD + (tid - IND)];
    }
    __syncthreads();
    for (int c = tid; c < BH; c += 512) {
        float v = Ss[c];
        for (int dd = 0; dd < BD; dd++) v += top[dd]*bp_w1[dd*BH + c];
        h1[c] = fmaxf(v, 0.f);
    }
    __syncthreads();
    for (int dd = tid; dd < BD; dd += 512) {
        float v = bp_b2[dd];
        for (int c = 0; c < BH; c++) v += h1[c]*bp_w2[c*BD + dd];
        ws[OFF_U + ((t + 17)*B + b)*BD + dd] = v;   // u_t -> slot t+17
    }
}

// Output head for all steps: out[b,t,o] = c_out[o] + sum_{l,d} u_{t-l}[b][d]*M[l][d][o]
// grid 208 = 16 b x 13 tiles of 8 t; thread covers o and o+256, 8 t-accumulators each.
__global__ __launch_bounds__(256) void k_q2(float* __restrict__ outs,
        const float* __restrict__ ws) {
    int b  = blockIdx.x / 13;
    int t0 = (blockIdx.x % 13) * 8;
    int tid = threadIdx.x;
    __shared__ float Uw[24*BD];
    const float* uh = ws + OFF_U;
    for (int idx = tid; idx < 24*BD; idx += 256) {
        int slot = t0 + 1 + idx/BD;
        int d = idx % BD;
        Uw[idx] = (slot < NSLOT) ? uh[(slot*B + b)*BD + d] : 0.f;
    }
    __syncthreads();
    int o0 = tid, o1 = tid + 256;
    bool v1 = o1 < OD;
    float a[8], c[8];
    #pragma unroll
    for (int i = 0; i < 8; i++) { a[i] = 0.f; c[i] = 0.f; }
    const float* M = ws + OFF_M;
    for (int l = 0; l < LBUF; l++) {
        const float* Mrow = M + l*BD*OD;
        const float* uwl = &Uw[(16 - l)*BD];
        for (int d = 0; d < BD; d++) {
            float m0 = Mrow[d*OD + o0];
            float m1 = v1 ? Mrow[d*OD + o1] : 0.f;
            const float* uw = uwl + d;
            #pragma unroll
            for (int tt = 0; tt < 8; tt++) {
                float u = uw[tt*BD];
                a[tt] += u*m0; c[tt] += u*m1;
            }
        }
    }
    float co0 = ws[OFF_CO + o0];
    float co1 = v1 ? ws[OFF_CO + o1] : 0.f;
    for (int tt = 0; tt < 8; tt++) {
        int tp = t0 + tt;
        if (tp < TDEC) {
            outs[(b*TDEC + tp)*OD + o0] = a[tt] + co0;
            if (v1) outs[(b*TDEC + tp)*OD + o1] = c[tt] + co1;
        }
    }
}

extern "C" void kernel_launch(void* const* d_in, const int* in_sizes, int n_in,
                              void* d_out, int out_size, void* d_ws, size_t ws_size,
                              hipStream_t stream) {
    const float* inputs  = (const float*)d_in[0];
    const float* targets = (const float*)d_in[1];
    const float* mp_w1   = (const float*)d_in[2];
    const float* mp_b1   = (const float*)d_in[3];
    const float* mp_w2   = (const float*)d_in[4];
    const float* mp_b2   = (const float*)d_in[5];
    const float* bp_w1   = (const float*)d_in[6];
    const float* bp_b1   = (const float*)d_in[7];
    const float* bp_w2   = (const float*)d_in[8];
    const float* bp_b2   = (const float*)d_in[9];
    const float* att_wq  = (const float*)d_in[10];
    const float* att_bq  = (const float*)d_in[11];
    const float* att_wa  = (const float*)d_in[12];
    const float* att_ba  = (const float*)d_in[13];
    const float* att_v   = (const float*)d_in[14];
    const float* scale_w = (const float*)d_in[15];
    const float* scale_b = (const float*)d_in[16];
    const float* out_w   = (const float*)d_in[17];
    const float* out_b   = (const float*)d_in[18];
    float* ws = (float*)d_ws;
    float* outs = (float*)d_out;
    float* attns = outs + B*TDEC*OD;

    k_init<<<(17*B*BD + OD + 255)/256, 256, 0, stream>>>(ws);
    k_pa  <<<B*TENC, 256, 0, stream>>>(inputs, att_wa, att_ba, ws);
    k_mem <<<TDEC*B, 128, 0, stream>>>(targets, mp_w1, mp_b1, mp_w2, mp_b2, ws);
    k_M   <<<17*14, 256, 0, stream>>>(scale_w, out_w, ws);
    k_cout<<<17, 256, 0, stream>>>(scale_b, out_w, out_b, ws);
    for (int t = 0; t < TDEC; t++) {
        k_step1<<<104, 256, 0, stream>>>(att_wq, bp_w1, ws, t);
        k_step2<<<B, 512, 0, stream>>>(inputs, att_bq, bp_b1, bp_w1, bp_b2, bp_w2,
                                       att_v, ws, attns, t);
    }
    k_q2<<<16*13, 256, 0, stream>>>(outs, ws);
}